// Round 1
// baseline (333.928 us; speedup 1.0000x reference)
//
#include <hip/hip_runtime.h>
#include <math.h>

// Problem constants (z: [16,4096,128] f32, emb_w: [1024,128] f32, unit rows)
#define D       128
#define NE      1024
#define NROWS   65536   // B*N
#define NB      16

// ---- output float offsets (total 16,924,675 floats) ----
#define OUT_ZQ    0            // [16,4096,128]
#define OUT_LOSS  8388608      // scalar
#define OUT_SAMP  8388609      // [16,1024]
#define OUT_IDX   8404993      // [16,4096] (float)
#define OUT_VAR   8470529      // scalar
#define OUT_DIST  8470530      // scalar
#define OUT_SI    8470531      // [16,4096] (float)
#define OUT_ZN    8536067      // [16,4096,128]  (NOT 16B-aligned -> scalar stores)

// ---- workspace float offsets (total 137,728 floats = 538 KB) ----
#define WS_IDX    0            // int[65536]
#define WS_WW     65536        // float[1024]
#define WS_FLAGS  66560        // int[1024]
#define WS_MIN2   67584        // float[1024]
#define WS_VAR    68608        // float[1024]
#define WS_LOSSP  69632        // float[512]
#define WS_COLSQP 70144        // float[512*128]
#define WS_COLSQ  135680       // float[16*128]

// numpy pairwise sum of squares over 128 contiguous floats:
// 8 accumulators over k%8, combined ((a0+a1)+(a2+a3))+((a4+a5)+(a6+a7)).
// __fmul_rn/__fadd_rn prevent fp-contract so we match np's rounding exactly.
__device__ __forceinline__ float npsq_sum128(const float* p) {
  float a[8];
#pragma unroll
  for (int m = 0; m < 8; ++m) a[m] = __fmul_rn(p[m], p[m]);
  for (int k = 8; k < 128; k += 8) {
#pragma unroll
    for (int m = 0; m < 8; ++m) a[m] = __fadd_rn(a[m], __fmul_rn(p[k + m], p[k + m]));
  }
  float s01 = __fadd_rn(a[0], a[1]);
  float s23 = __fadd_rn(a[2], a[3]);
  float s45 = __fadd_rn(a[4], a[5]);
  float s67 = __fadd_rn(a[6], a[7]);
  return __fadd_rn(__fadd_rn(s01, s23), __fadd_rn(s45, s67));
}

// ---- ww[c] = sum(w[c]^2), numpy order ----
__global__ __launch_bounds__(128) void k_ww(const float* __restrict__ w,
                                            float* __restrict__ ws) {
  int c = blockIdx.x * 128 + threadIdx.x;
  if (c >= NE) return;
  ws[WS_WW + c] = npsq_sum128(w + c * D);
}

// ---- codebook self-distance stats: per row i, second-min and unbiased var ----
__global__ __launch_bounds__(128) void k_cb(const float* __restrict__ w,
                                            float* __restrict__ ws) {
  const int i = blockIdx.x;   // row 0..1023
  const int t = threadIdx.x;  // 0..127
  __shared__ float4 wi[32];
  __shared__ float r1[128], r2[128], rs[128], rq[128];
  if (t < 32) wi[t] = ((const float4*)(w + i * D))[t];
  __syncthreads();
  const float wwi = ws[WS_WW + i];
  float m1 = INFINITY, m2 = INFINITY, sum = 0.f, sq = 0.f;
  for (int jj = 0; jj < 8; ++jj) {
    int j = t + jj * 128;
    const float4* pj = (const float4*)(w + j * D);
    float acc = 0.f;
#pragma unroll
    for (int k4 = 0; k4 < 32; ++k4) {
      float4 a = wi[k4], b = pj[k4];
      acc = fmaf(a.x, b.x, acc); acc = fmaf(a.y, b.y, acc);
      acc = fmaf(a.z, b.z, acc); acc = fmaf(a.w, b.w, acc);
    }
    float t1 = __fadd_rn(wwi, ws[WS_WW + j]);
    float d  = __fsub_rn(t1, __fmul_rn(2.f, acc));
    sum += d; sq = fmaf(d, d, sq);
    if (d < m1) { m2 = m1; m1 = d; } else if (d < m2) m2 = d;
  }
  r1[t] = m1; r2[t] = m2; rs[t] = sum; rq[t] = sq;
  __syncthreads();
  for (int s = 64; s > 0; s >>= 1) {
    if (t < s) {
      float a1 = r1[t], a2 = r2[t], b1 = r1[t + s], b2 = r2[t + s];
      r1[t] = fminf(a1, b1);
      r2[t] = fminf(fmaxf(a1, b1), fminf(a2, b2));
      rs[t] += rs[t + s]; rq[t] += rq[t + s];
    }
    __syncthreads();
  }
  if (t == 0) {
    ws[WS_MIN2 + i] = r2[0];
    float S = rs[0], Q = rq[0];
    ws[WS_VAR + i] = (Q - S * S / (float)NE) / (float)(NE - 1);
  }
}

// ---- main quantization: fused fp32 GEMM + argmin ----
// 512 blocks x 512 threads; tile 128 rows x all 1024 codes (8 chunks of 128).
// micro-tile 8 rows x 4 cols per thread. LDS 135.7 KB -> 1 block/CU, 8 waves.
#define TM  128
#define TNC 128
#define NCH 8
#define LDP 132   // padded LDS row stride (floats)

__global__ __launch_bounds__(512) void k_argmin(const float* __restrict__ z,
                                                const float* __restrict__ w,
                                                float* __restrict__ ws,
                                                float* __restrict__ out) {
  __shared__ float zs[TM * LDP];
  __shared__ float wt[TNC * LDP];
  __shared__ float zzs[TM];
  const int t   = threadIdx.x;
  const int blk = blockIdx.x;
  const int tx  = t & 31;   // col group (cols tx, tx+32, tx+64, tx+96)
  const int ty  = t >> 5;   // row group (rows ty*8 .. ty*8+7)
  const int r0  = ty * 8;

  // stage z tile (coalesced float4)
  {
    const float4* zg = (const float4*)(z + (size_t)blk * TM * D);
#pragma unroll
    for (int it = 0; it < 8; ++it) {
      int u = it * 512 + t;
      int row = u >> 5, c4 = u & 31;
      float4 v = zg[u];
      *(float4*)&zs[row * LDP + c4 * 4] = v;
    }
  }
  __syncthreads();
  if (t < TM) zzs[t] = npsq_sum128(zs + t * LDP);  // note: LDP-strided rows, first 128 used

  float best[8]; int bidx[8];
#pragma unroll
  for (int i = 0; i < 8; ++i) { best[i] = INFINITY; bidx[i] = 0; }

  for (int ci = 0; ci < NCH; ++ci) {
    __syncthreads();
    { // stage w chunk
      const float4* wg = (const float4*)(w + (size_t)ci * TNC * D);
#pragma unroll
      for (int it = 0; it < 8; ++it) {
        int u = it * 512 + t;
        int row = u >> 5, c4 = u & 31;
        float4 v = wg[u];
        *(float4*)&wt[row * LDP + c4 * 4] = v;
      }
    }
    __syncthreads();
    float acc[8][4];
#pragma unroll
    for (int i = 0; i < 8; ++i)
#pragma unroll
      for (int j = 0; j < 4; ++j) acc[i][j] = 0.f;

#pragma unroll 2
    for (int ks = 0; ks < 32; ++ks) {
      float4 az[8], bw[4];
#pragma unroll
      for (int i = 0; i < 8; ++i) az[i] = *(const float4*)&zs[(r0 + i) * LDP + ks * 4];
#pragma unroll
      for (int j = 0; j < 4; ++j) bw[j] = *(const float4*)&wt[(tx + 32 * j) * LDP + ks * 4];
#pragma unroll
      for (int i = 0; i < 8; ++i)
#pragma unroll
        for (int j = 0; j < 4; ++j) {
          acc[i][j] = fmaf(az[i].x, bw[j].x, acc[i][j]);
          acc[i][j] = fmaf(az[i].y, bw[j].y, acc[i][j]);
          acc[i][j] = fmaf(az[i].z, bw[j].z, acc[i][j]);
          acc[i][j] = fmaf(az[i].w, bw[j].w, acc[i][j]);
        }
    }
    // epilogue: d = fl(fl(zz+ww) - 2*dot); ascending code order per thread
#pragma unroll
    for (int j = 0; j < 4; ++j) {
      int c = ci * TNC + tx + 32 * j;
      float wwc = ws[WS_WW + c];
#pragma unroll
      for (int i = 0; i < 8; ++i) {
        float t1 = __fadd_rn(zzs[r0 + i], wwc);
        float d  = __fsub_rn(t1, __fmul_rn(2.f, acc[i][j]));
        if (d < best[i]) { best[i] = d; bidx[i] = c; }
      }
    }
  }

  // cross-thread reduce per row: lexicographic (val, idx) min == first argmin
  __syncthreads();
  float* redV = wt;                 // [TM*32]
  int*   redI = (int*)(wt + TM * 32);
#pragma unroll
  for (int i = 0; i < 8; ++i) {
    redV[(r0 + i) * 32 + tx] = best[i];
    redI[(r0 + i) * 32 + tx] = bidx[i];
  }
  __syncthreads();
  if (t < TM) {
    int base = t * 32;
    float m = redV[base]; int mi = redI[base];
    for (int x = 1; x < 32; ++x) {
      float v = redV[base + x]; int ii = redI[base + x];
      if (v < m || (v == m && ii < mi)) { m = v; mi = ii; }
    }
    int gr = blk * TM + t;
    ((int*)ws)[WS_IDX + gr] = mi;
    out[OUT_IDX + gr] = (float)mi;
    out[OUT_SI  + gr] = (float)mi;
    ((int*)ws)[WS_FLAGS + mi] = 1;   // benign race: all writers store 1
  }
}

// ---- gather z_q -> out0, loss partials, per-column square partials ----
// 512 blocks x 256 threads, 128 rows/block.
__global__ __launch_bounds__(256) void k_gather(const float* __restrict__ z,
                                                const float* __restrict__ w,
                                                float* __restrict__ ws,
                                                float* __restrict__ out) {
  __shared__ float csp[32][8][4];  // [c4][rowgroup][component]
  __shared__ float lred[256];
  const int t = threadIdx.x, blk = blockIdx.x;
  const int c4 = t & 31, rg = t >> 5;  // rg 0..7
  float lp = 0.f;
  float csx = 0.f, csy = 0.f, csz = 0.f, csw = 0.f;
  for (int m = 0; m < 16; ++m) {
    int r  = rg + 8 * m;
    int gr = blk * 128 + r;
    int idx = ((const int*)ws)[WS_IDX + gr];
    float4 q  = *(const float4*)&w[idx * D + c4 * 4];
    float4 zv = *(const float4*)&z[(size_t)gr * D + c4 * 4];
    *(float4*)&out[OUT_ZQ + (size_t)gr * D + c4 * 4] = q;  // z_q_st == z_q
    float dx = q.x - zv.x, dy = q.y - zv.y, dz = q.z - zv.z, dw = q.w - zv.w;
    lp = fmaf(dx, dx, lp); lp = fmaf(dy, dy, lp);
    lp = fmaf(dz, dz, lp); lp = fmaf(dw, dw, lp);
    csx = fmaf(q.x, q.x, csx); csy = fmaf(q.y, q.y, csy);
    csz = fmaf(q.z, q.z, csz); csw = fmaf(q.w, q.w, csw);
  }
  csp[c4][rg][0] = csx; csp[c4][rg][1] = csy;
  csp[c4][rg][2] = csz; csp[c4][rg][3] = csw;
  lred[t] = lp;
  __syncthreads();
  for (int s = 128; s > 0; s >>= 1) {
    if (t < s) lred[t] += lred[t + s];
    __syncthreads();
  }
  if (t == 0) ws[WS_LOSSP + blk] = lred[0];
  if (t < 128) {
    int dcol = t;
    float s = 0.f;
    for (int g = 0; g < 8; ++g) s += csp[dcol >> 2][g][dcol & 3];
    ws[WS_COLSQP + blk * 128 + dcol] = s;
  }
}

// ---- combine colsq partials (deterministic fixed order) ----
__global__ __launch_bounds__(256) void k_colsq_final(float* __restrict__ ws) {
  int t = blockIdx.x * 256 + threadIdx.x;  // 0..2047 = (b,d)
  if (t >= NB * D) return;
  int b = t >> 7, dcol = t & 127;
  float s = 0.f;
  for (int rb = 0; rb < 32; ++rb)          // 32 row-blocks per batch
    s += ws[WS_COLSQP + (b * 32 + rb) * 128 + dcol];
  ws[WS_COLSQ + t] = s;
}

// ---- zn = z_q / max(||z_q[b,:,d]||, 1e-12)  (normalize over N axis) ----
__global__ __launch_bounds__(256) void k_zn(const float* __restrict__ ws,
                                            float* __restrict__ out) {
  int u = blockIdx.x * 256 + threadIdx.x;
  const int total4 = NROWS * D / 4;
  for (; u < total4; u += gridDim.x * 256) {
    float4 q = ((const float4*)out)[u];   // reads OUT_ZQ region (offset 0)
    int o = u * 4;
    int b = o >> 19;          // 4096*128 = 2^19 floats per batch
    int dcol = o & 127;
    float4 cs = *(const float4*)&ws[WS_COLSQ + b * 128 + dcol];
    // OUT_ZN is not 16B aligned -> scalar stores
    out[OUT_ZN + o + 0] = q.x / fmaxf(sqrtf(cs.x), 1e-12f);
    out[OUT_ZN + o + 1] = q.y / fmaxf(sqrtf(cs.y), 1e-12f);
    out[OUT_ZN + o + 2] = q.z / fmaxf(sqrtf(cs.z), 1e-12f);
    out[OUT_ZN + o + 3] = q.w / fmaxf(sqrtf(cs.w), 1e-12f);
  }
}

// ---- finalize scalars + sampled_idx ----
__global__ __launch_bounds__(1024) void k_final(float* __restrict__ ws,
                                                float* __restrict__ out) {
  __shared__ float s1[1024], s2[1024], s3[1024];
  int t = threadIdx.x;
  s1[t] = (t < 512) ? ws[WS_LOSSP + t] : 0.f;
  s2[t] = ws[WS_MIN2 + t];
  s3[t] = ws[WS_VAR + t];
  __syncthreads();
  for (int s = 512; s > 0; s >>= 1) {
    if (t < s) { s1[t] += s1[t + s]; s2[t] += s2[t + s]; s3[t] += s3[t + s]; }
    __syncthreads();
  }
  if (t == 0) {
    float m = s1[0] / 8388608.f;            // mean((z_q - z)^2)
    out[OUT_LOSS] = m + 0.9f * m;           // + BETA * same
    out[OUT_VAR]  = s3[0] / 1024.f;
    out[OUT_DIST] = s2[0] / 1024.f;
  }
  const int* flags = (const int*)ws + WS_FLAGS;
  for (int i = t; i < NB * NE; i += 1024)
    out[OUT_SAMP + i] = (i < NE && flags[i] != 0) ? 1.f : 0.f;
}

extern "C" void kernel_launch(void* const* d_in, const int* in_sizes, int n_in,
                              void* d_out, int out_size, void* d_ws, size_t ws_size,
                              hipStream_t stream) {
  const float* z = (const float*)d_in[0];   // [16,4096,128]
  const float* w = (const float*)d_in[1];   // [1024,128]
  float* out = (float*)d_out;               // 16,924,675 floats
  float* ws  = (float*)d_ws;                // needs 550,912 bytes

  hipMemsetAsync((char*)d_ws + (size_t)WS_FLAGS * 4, 0, NE * 4, stream);
  hipLaunchKernelGGL(k_ww,          dim3(8),    dim3(128),  0, stream, w, ws);
  hipLaunchKernelGGL(k_cb,          dim3(1024), dim3(128),  0, stream, w, ws);
  hipLaunchKernelGGL(k_argmin,      dim3(512),  dim3(512),  0, stream, z, w, ws, out);
  hipLaunchKernelGGL(k_gather,      dim3(512),  dim3(256),  0, stream, z, w, ws, out);
  hipLaunchKernelGGL(k_colsq_final, dim3(8),    dim3(256),  0, stream, ws);
  hipLaunchKernelGGL(k_zn,          dim3(2048), dim3(256),  0, stream, ws, out);
  hipLaunchKernelGGL(k_final,       dim3(1),    dim3(1024), 0, stream, ws, out);
}